// Round 1
// baseline (264.136 us; speedup 1.0000x reference)
//
#include <hip/hip_runtime.h>
#include <hip/hip_bf16.h>
#include <stdint.h>

// Problem: out[8192,4096] = x[8192,2048] @ WeffT^T, WeffT built from W (4096,2048).
#define M_DIM 8192
#define K_DIM 2048
#define N_DIM 4096
#define BM 128
#define BN 128
#define BK 32

typedef __attribute__((ext_vector_type(8))) short bf16x8;
typedef __attribute__((ext_vector_type(4))) float f32x4;

__device__ __forceinline__ unsigned short f2bfu(float f) {
    __hip_bfloat16 h = __float2bfloat16(f);
    return __builtin_bit_cast(unsigned short, h);
}

// ---------------------------------------------------------------------------
// Kernel 1: WeffT[o][i] (N x K, row-major, bf16) =
//   W[o][i] + W[o][IN-1-i] + W[OUT-1-o][i]
//   + sum_{s=1..5} ( W[o][(i-s) mod IN] + W[(o-s) mod OUT][i] )
// ---------------------------------------------------------------------------
__global__ void build_weff(const float* __restrict__ W, unsigned short* __restrict__ WT) {
    const int o = blockIdx.x;
    const float* wo  = W + (size_t)o * K_DIM;
    const float* wfo = W + (size_t)(N_DIM - 1 - o) * K_DIM;
    const float* wr0 = W + (size_t)((o - 1) & (N_DIM - 1)) * K_DIM;
    const float* wr1 = W + (size_t)((o - 2) & (N_DIM - 1)) * K_DIM;
    const float* wr2 = W + (size_t)((o - 3) & (N_DIM - 1)) * K_DIM;
    const float* wr3 = W + (size_t)((o - 4) & (N_DIM - 1)) * K_DIM;
    const float* wr4 = W + (size_t)((o - 5) & (N_DIM - 1)) * K_DIM;
    for (int i = threadIdx.x; i < K_DIM; i += 256) {
        float acc = wo[i] + wo[K_DIM - 1 - i] + wfo[i];
        acc += wo[(i - 1) & (K_DIM - 1)];
        acc += wo[(i - 2) & (K_DIM - 1)];
        acc += wo[(i - 3) & (K_DIM - 1)];
        acc += wo[(i - 4) & (K_DIM - 1)];
        acc += wo[(i - 5) & (K_DIM - 1)];
        acc += wr0[i] + wr1[i] + wr2[i] + wr3[i] + wr4[i];
        WT[(size_t)o * K_DIM + i] = f2bfu(acc);
    }
}

// ---------------------------------------------------------------------------
// Kernel 2: x fp32 -> bf16 (vectorized float4 -> ushort4)
// ---------------------------------------------------------------------------
__global__ void cvt_x_kernel(const float* __restrict__ x, unsigned short* __restrict__ xb) {
    const int idx = blockIdx.x * 256 + threadIdx.x;
    float4 v = ((const float4*)x)[idx];
    ushort4 o;
    o.x = f2bfu(v.x); o.y = f2bfu(v.y); o.z = f2bfu(v.z); o.w = f2bfu(v.w);
    ((ushort4*)xb)[idx] = o;
}

// ---------------------------------------------------------------------------
// Kernel 3: bf16 MFMA GEMM, m97 structure: 128x128 tile, BK=32, 4 waves (2x2),
// 4x4 16x16x32 acc per wave, global_load_lds width-16 staging, B^T input.
// ---------------------------------------------------------------------------
template <bool A_BF16>
__global__ __launch_bounds__(256) void gemm_bt(const void* __restrict__ Aptr,
                                               const unsigned short* __restrict__ Bt,
                                               float* __restrict__ C) {
    __shared__ __align__(16) unsigned short As[BM * BK];
    __shared__ __align__(16) unsigned short Bs[BN * BK];

    const int tid  = threadIdx.x;
    const int wave = tid >> 6;
    const int lane = tid & 63;

    // XCD-bijective swizzle (nwg = 2048, divisible by 8)
    const int nwg = gridDim.x;
    const int cpx = nwg >> 3;
    const int wg  = (blockIdx.x & 7) * cpx + (blockIdx.x >> 3);
    const int nbn = N_DIM / BN;                 // 32
    const int bm0 = (wg / nbn) * BM;
    const int bn0 = (wg % nbn) * BN;

    const int wr = wave >> 1;                   // 0..1
    const int wc = wave & 1;                    // 0..1

    const unsigned short* Ab = (const unsigned short*)Aptr;
    const float*          Af = (const float*)Aptr;

    f32x4 acc[4][4] = {};

    for (int k0 = 0; k0 < K_DIM; k0 += BK) {
        __syncthreads();
        // ---- stage B tile (128 rows of WT x 32 k) : 8192 B, 2 issues ----
#pragma unroll
        for (int j = 0; j < 2; ++j) {
            const int eo  = j * 2048 + wave * 512 + lane * 8;   // element offset
            const int row = eo >> 5, col = eo & 31;
            const unsigned short* g = Bt + (size_t)(bn0 + row) * K_DIM + k0 + col;
            unsigned short* l = (unsigned short*)Bs + j * 2048 + wave * 512; // wave-uniform
            __builtin_amdgcn_global_load_lds(
                (const __attribute__((address_space(1))) unsigned int*)g,
                (__attribute__((address_space(3))) unsigned int*)l, 16, 0, 0);
        }
        if constexpr (A_BF16) {
            // ---- stage A tile via global_load_lds ----
#pragma unroll
            for (int j = 0; j < 2; ++j) {
                const int eo  = j * 2048 + wave * 512 + lane * 8;
                const int row = eo >> 5, col = eo & 31;
                const unsigned short* g = Ab + (size_t)(bm0 + row) * K_DIM + k0 + col;
                unsigned short* l = (unsigned short*)As + j * 2048 + wave * 512;
                __builtin_amdgcn_global_load_lds(
                    (const __attribute__((address_space(1))) unsigned int*)g,
                    (__attribute__((address_space(3))) unsigned int*)l, 16, 0, 0);
            }
        } else {
            // ---- fallback: A is fp32 in HBM; reg-stage + convert ----
#pragma unroll
            for (int j = 0; j < 4; ++j) {
                const int eo  = j * 1024 + tid * 4;
                const int row = eo >> 5, col = eo & 31;
                float4 v = *(const float4*)(Af + (size_t)(bm0 + row) * K_DIM + k0 + col);
                ushort4 o;
                o.x = f2bfu(v.x); o.y = f2bfu(v.y); o.z = f2bfu(v.z); o.w = f2bfu(v.w);
                *(ushort4*)&As[eo] = o;
            }
        }
        __syncthreads();

        // ---- fragments + MFMA ----
        const int half = lane >> 4;   // 0..3 -> k = half*8 + j
        const int r16  = lane & 15;
        bf16x8 a[4], b[4];
#pragma unroll
        for (int mi = 0; mi < 4; ++mi)
            a[mi] = *(const bf16x8*)&As[(wr * 64 + mi * 16 + r16) * BK + half * 8];
#pragma unroll
        for (int ni = 0; ni < 4; ++ni)
            b[ni] = *(const bf16x8*)&Bs[(wc * 64 + ni * 16 + r16) * BK + half * 8];
#pragma unroll
        for (int mi = 0; mi < 4; ++mi)
#pragma unroll
            for (int ni = 0; ni < 4; ++ni)
                acc[mi][ni] = __builtin_amdgcn_mfma_f32_16x16x32_bf16(a[mi], b[ni], acc[mi][ni], 0, 0, 0);
    }

    // ---- epilogue: D col = lane&15, row = (lane>>4)*4 + r ----
    const int crow = (lane >> 4) * 4;
    const int ccol = lane & 15;
#pragma unroll
    for (int mi = 0; mi < 4; ++mi)
#pragma unroll
        for (int ni = 0; ni < 4; ++ni)
#pragma unroll
            for (int r = 0; r < 4; ++r)
                C[(size_t)(bm0 + wr * 64 + mi * 16 + crow + r) * N_DIM
                  + (bn0 + wc * 64 + ni * 16 + ccol)] = acc[mi][ni][r];
}

// ---------------------------------------------------------------------------
extern "C" void kernel_launch(void* const* d_in, const int* in_sizes, int n_in,
                              void* d_out, int out_size, void* d_ws, size_t ws_size,
                              hipStream_t stream) {
    const float* x = (const float*)d_in[0];   // (4,2048,2048) fp32
    const float* W = (const float*)d_in[1];   // (4096,2048) fp32
    float* out = (float*)d_out;               // (4,2048,4096) fp32

    const size_t xb_bytes = (size_t)M_DIM * K_DIM * 2;  // 32 MB
    const size_t wt_bytes = (size_t)N_DIM * K_DIM * 2;  // 16 MB

    unsigned short* xb = nullptr;
    unsigned short* wt = nullptr;
    bool a_bf16 = false;
    if (ws_size >= xb_bytes + wt_bytes) {
        xb = (unsigned short*)d_ws;
        wt = (unsigned short*)((char*)d_ws + xb_bytes);
        a_bf16 = true;
    } else {
        // need at least 16 MB for WeffT; A stays fp32 and is converted in-kernel
        wt = (unsigned short*)d_ws;
    }

    build_weff<<<N_DIM, 256, 0, stream>>>(W, wt);
    if (a_bf16)
        cvt_x_kernel<<<(M_DIM * K_DIM) / 4 / 256, 256, 0, stream>>>(x, xb);

    dim3 grid((M_DIM / BM) * (N_DIM / BN));   // 2048 blocks
    if (a_bf16)
        gemm_bt<true><<<grid, 256, 0, stream>>>((const void*)xb, wt, out);
    else
        gemm_bt<false><<<grid, 256, 0, stream>>>((const void*)x, wt, out);
}

// Round 2
// 186.657 us; speedup vs baseline: 1.4151x; 1.4151x over previous
//
#include <hip/hip_runtime.h>
#include <hip/hip_bf16.h>
#include <stdint.h>

// out[8192,4096] = x[8192,2048] @ WeffT^T ; WeffT built from W (4096,2048).
#define M_DIM 8192
#define K_DIM 2048
#define N_DIM 4096
#define BM 256
#define BN 256
#define BK 64
#define NT (K_DIM / BK)   // 32 K-tiles

typedef __attribute__((ext_vector_type(8))) short bf16x8;
typedef __attribute__((ext_vector_type(4))) float f32x4;

__device__ __forceinline__ unsigned short f2bfu(float f) {
    __hip_bfloat16 h = __float2bfloat16(f);
    return __builtin_bit_cast(unsigned short, h);
}

// ---------------------------------------------------------------------------
// Kernel 1: WeffT[o][i] (N x K row-major, bf16)
// ---------------------------------------------------------------------------
__global__ void build_weff(const float* __restrict__ W, unsigned short* __restrict__ WT) {
    const int o = blockIdx.x;
    const float* wo  = W + (size_t)o * K_DIM;
    const float* wfo = W + (size_t)(N_DIM - 1 - o) * K_DIM;
    const float* wr0 = W + (size_t)((o - 1) & (N_DIM - 1)) * K_DIM;
    const float* wr1 = W + (size_t)((o - 2) & (N_DIM - 1)) * K_DIM;
    const float* wr2 = W + (size_t)((o - 3) & (N_DIM - 1)) * K_DIM;
    const float* wr3 = W + (size_t)((o - 4) & (N_DIM - 1)) * K_DIM;
    const float* wr4 = W + (size_t)((o - 5) & (N_DIM - 1)) * K_DIM;
    for (int i = threadIdx.x; i < K_DIM; i += 256) {
        float acc = wo[i] + wo[K_DIM - 1 - i] + wfo[i];
        acc += wo[(i - 1) & (K_DIM - 1)];
        acc += wo[(i - 2) & (K_DIM - 1)];
        acc += wo[(i - 3) & (K_DIM - 1)];
        acc += wo[(i - 4) & (K_DIM - 1)];
        acc += wo[(i - 5) & (K_DIM - 1)];
        acc += wr0[i] + wr1[i] + wr2[i] + wr3[i] + wr4[i];
        WT[(size_t)o * K_DIM + i] = f2bfu(acc);
    }
}

// ---------------------------------------------------------------------------
// Kernel 2: x fp32 -> bf16
// ---------------------------------------------------------------------------
__global__ void cvt_x_kernel(const float* __restrict__ x, unsigned short* __restrict__ xb) {
    const int idx = blockIdx.x * 256 + threadIdx.x;
    float4 v = ((const float4*)x)[idx];
    ushort4 o;
    o.x = f2bfu(v.x); o.y = f2bfu(v.y); o.z = f2bfu(v.z); o.w = f2bfu(v.w);
    ((ushort4*)xb)[idx] = o;
}

// ---------------------------------------------------------------------------
// Kernel 3: 256x256 tile, BK=64, 8 waves (2Mx4N), double-buffered LDS,
// counted vmcnt(8) (T4), raw barriers (2/K-tile), XOR slot swizzle (T2),
// setprio around MFMA clusters (T5). 64 MFMA/wave per barrier-pair.
//
// LDS layout per buffer p (64 KiB): A[256][64] bf16 at p*65536,
// B[256][64] at p*65536+32768. Row = 128 B = 8 x 16B slots.
// Physical slot = logical slot ^ (row & 7)  (applied on BOTH the
// pre-swizzled global source of global_load_lds and the ds_read addr).
// ---------------------------------------------------------------------------
__global__ __launch_bounds__(512, 2) void gemm256(const unsigned short* __restrict__ Ab,
                                                  const unsigned short* __restrict__ Bt,
                                                  float* __restrict__ C) {
    __shared__ __align__(16) char smem[2 * 65536];

    const int tid  = threadIdx.x;
    const int wave = tid >> 6;
    const int lane = tid & 63;

    // XCD-bijective swizzle: nwg = 512, divisible by 8
    const int nwg = gridDim.x;
    const int cpx = nwg >> 3;
    const int wg  = (blockIdx.x & 7) * cpx + (blockIdx.x >> 3);
    const int nbn = N_DIM / BN;                // 16
    const int bm0 = (wg / nbn) * BM;
    const int bn0 = (wg % nbn) * BN;

    const int wr = wave >> 2;                  // 0..1 (M)
    const int wc = wave & 3;                   // 0..3 (N)

    // ---- staging addresses (pre-swizzled global source) ----
    // issue j covers rows j*64..j*64+63; this thread: row = j*64+srow, slot lsw
    const int srow = wave * 8 + (lane >> 3);            // 0..63
    const int lsw  = (lane & 7) ^ ((lane >> 3) & 7);    // logical slot fetched
    const unsigned short* gA0 = Ab + (size_t)(bm0 + srow) * K_DIM + lsw * 8;
    const unsigned short* gB0 = Bt + (size_t)(bn0 + srow) * K_DIM + lsw * 8;

    // ---- ds_read addressing (swizzled) ----
    const int r16   = lane & 15;
    const int slot0 = (((lane >> 4) | 0) ^ (lane & 7)) * 16;   // kk=0
    const int slot1 = (((lane >> 4) | 4) ^ (lane & 7)) * 16;   // kk=1
    const int aRow  = (wr * 128 + r16) * 128;  // byte offset of row in A buf
    const int bRow  = (wc * 64  + r16) * 128;  // byte offset of row in B buf

    f32x4 acc[8][4] = {};

#define STAGE(kt, p) do {                                                          \
    char* ldsA = smem + (p) * 65536 + wave * 1024;                                 \
    char* ldsB = ldsA + 32768;                                                     \
    const unsigned short* ga = gA0 + (kt) * BK;                                    \
    const unsigned short* gb = gB0 + (kt) * BK;                                    \
    _Pragma("unroll")                                                              \
    for (int j = 0; j < 4; ++j)                                                    \
        __builtin_amdgcn_global_load_lds(                                          \
            (const __attribute__((address_space(1))) unsigned int*)(ga + (size_t)j * 64 * K_DIM), \
            (__attribute__((address_space(3))) unsigned int*)(ldsA + j * 8192),    \
            16, 0, 0);                                                             \
    _Pragma("unroll")                                                              \
    for (int j = 0; j < 4; ++j)                                                    \
        __builtin_amdgcn_global_load_lds(                                          \
            (const __attribute__((address_space(1))) unsigned int*)(gb + (size_t)j * 64 * K_DIM), \
            (__attribute__((address_space(3))) unsigned int*)(ldsB + j * 8192),    \
            16, 0, 0);                                                             \
} while (0)

    // prologue: tiles 0 and 1 in flight (16 loads/thread)
    STAGE(0, 0);
    STAGE(1, 1);

    for (int k = 0; k < NT; ++k) {
        const int p = k & 1;

        // tile k fully landed; tile k+1's 8 loads stay in flight (T4)
        if (k + 1 < NT) asm volatile("s_waitcnt vmcnt(8)" ::: "memory");
        else            asm volatile("s_waitcnt vmcnt(0)" ::: "memory");
        __builtin_amdgcn_s_barrier();
        __builtin_amdgcn_sched_barrier(0);

        const char* bufA = smem + p * 65536;
        const char* bufB = bufA + 32768;

        bf16x8 b[4][2];
#pragma unroll
        for (int fn = 0; fn < 4; ++fn) {
            b[fn][0] = *(const bf16x8*)(bufB + bRow + fn * (16 * 128) + slot0);
            b[fn][1] = *(const bf16x8*)(bufB + bRow + fn * (16 * 128) + slot1);
        }
#pragma unroll
        for (int qm = 0; qm < 2; ++qm) {
            bf16x8 a[4][2];
#pragma unroll
            for (int fm = 0; fm < 4; ++fm) {
                a[fm][0] = *(const bf16x8*)(bufA + aRow + (qm * 64 + fm * 16) * 128 + slot0);
                a[fm][1] = *(const bf16x8*)(bufA + aRow + (qm * 64 + fm * 16) * 128 + slot1);
            }
            __builtin_amdgcn_s_setprio(1);
#pragma unroll
            for (int fm = 0; fm < 4; ++fm)
#pragma unroll
                for (int fn = 0; fn < 4; ++fn) {
                    acc[qm * 4 + fm][fn] = __builtin_amdgcn_mfma_f32_16x16x32_bf16(
                        a[fm][0], b[fn][0], acc[qm * 4 + fm][fn], 0, 0, 0);
                    acc[qm * 4 + fm][fn] = __builtin_amdgcn_mfma_f32_16x16x32_bf16(
                        a[fm][1], b[fn][1], acc[qm * 4 + fm][fn], 0, 0, 0);
                }
            __builtin_amdgcn_s_setprio(0);
        }

        // all my ds_reads of buf[p] returned before signaling
        asm volatile("s_waitcnt lgkmcnt(0)" ::: "memory");
        __builtin_amdgcn_sched_barrier(0);
        __builtin_amdgcn_s_barrier();
        __builtin_amdgcn_sched_barrier(0);

        // buf[p] free for everyone -> stage tile k+2 into it (lands >= issue)
        if (k + 2 < NT) STAGE(k + 2, p);
    }
#undef STAGE

    // ---- epilogue: D col = lane&15, row = (lane>>4)*4 + r ----
    const int crow = (lane >> 4) * 4;
    const int ccol = lane & 15;
    float* Cb = C + (size_t)(bm0 + wr * 128 + crow) * N_DIM + (bn0 + wc * 64 + ccol);
#pragma unroll
    for (int fm = 0; fm < 8; ++fm)
#pragma unroll
        for (int fn = 0; fn < 4; ++fn)
#pragma unroll
            for (int r = 0; r < 4; ++r)
                Cb[(size_t)(fm * 16 + r) * N_DIM + fn * 16] = acc[fm][fn][r];
}

// ---------------------------------------------------------------------------
extern "C" void kernel_launch(void* const* d_in, const int* in_sizes, int n_in,
                              void* d_out, int out_size, void* d_ws, size_t ws_size,
                              hipStream_t stream) {
    const float* x = (const float*)d_in[0];   // (4,2048,2048) fp32
    const float* W = (const float*)d_in[1];   // (4096,2048) fp32
    float* out = (float*)d_out;               // (4,2048,4096) fp32

    unsigned short* xb = (unsigned short*)d_ws;                         // 32 MB bf16 x
    unsigned short* wt = (unsigned short*)((char*)d_ws + (size_t)M_DIM * K_DIM * 2); // 16 MB WeffT

    build_weff<<<N_DIM, 256, 0, stream>>>(W, wt);
    cvt_x_kernel<<<(M_DIM * K_DIM) / 4 / 256, 256, 0, stream>>>(x, xb);

    dim3 grid((M_DIM / BM) * (N_DIM / BN));   // 512 blocks
    gemm256<<<grid, 512, 0, stream>>>(xb, wt, out);
}

// Round 3
// 179.889 us; speedup vs baseline: 1.4683x; 1.0376x over previous
//
#include <hip/hip_runtime.h>
#include <hip/hip_bf16.h>
#include <stdint.h>

// out[8192,4096] = x[8192,2048] @ WeffT^T ; WeffT built from W (4096,2048).
#define M_DIM 8192
#define K_DIM 2048
#define N_DIM 4096
#define BM 256
#define BN 256
#define BK 64
#define NT (K_DIM / BK)    // 32 K-tiles
#define NITER (NT / 2)     // 16 iterations, 2 K-tiles each

typedef __attribute__((ext_vector_type(8))) short bf16x8;
typedef __attribute__((ext_vector_type(4))) float f32x4;

__device__ __forceinline__ unsigned short f2bfu(float f) {
    __hip_bfloat16 h = __float2bfloat16(f);
    return __builtin_bit_cast(unsigned short, h);
}

// ---------------------------------------------------------------------------
// Kernel 1: WeffT[o][i] (N x K row-major, bf16)
// ---------------------------------------------------------------------------
__global__ void build_weff(const float* __restrict__ W, unsigned short* __restrict__ WT) {
    const int o = blockIdx.x;
    const float* wo  = W + (size_t)o * K_DIM;
    const float* wfo = W + (size_t)(N_DIM - 1 - o) * K_DIM;
    const float* wr0 = W + (size_t)((o - 1) & (N_DIM - 1)) * K_DIM;
    const float* wr1 = W + (size_t)((o - 2) & (N_DIM - 1)) * K_DIM;
    const float* wr2 = W + (size_t)((o - 3) & (N_DIM - 1)) * K_DIM;
    const float* wr3 = W + (size_t)((o - 4) & (N_DIM - 1)) * K_DIM;
    const float* wr4 = W + (size_t)((o - 5) & (N_DIM - 1)) * K_DIM;
    for (int i = threadIdx.x; i < K_DIM; i += 256) {
        float acc = wo[i] + wo[K_DIM - 1 - i] + wfo[i];
        acc += wo[(i - 1) & (K_DIM - 1)];
        acc += wo[(i - 2) & (K_DIM - 1)];
        acc += wo[(i - 3) & (K_DIM - 1)];
        acc += wo[(i - 4) & (K_DIM - 1)];
        acc += wo[(i - 5) & (K_DIM - 1)];
        acc += wr0[i] + wr1[i] + wr2[i] + wr3[i] + wr4[i];
        WT[(size_t)o * K_DIM + i] = f2bfu(acc);
    }
}

// ---------------------------------------------------------------------------
// Kernel 2: x fp32 -> bf16
// ---------------------------------------------------------------------------
__global__ void cvt_x_kernel(const float* __restrict__ x, unsigned short* __restrict__ xb) {
    const int idx = blockIdx.x * 256 + threadIdx.x;
    float4 v = ((const float4*)x)[idx];
    ushort4 o;
    o.x = f2bfu(v.x); o.y = f2bfu(v.y); o.z = f2bfu(v.z); o.w = f2bfu(v.w);
    ((ushort4*)xb)[idx] = o;
}

// ---------------------------------------------------------------------------
// Kernel 3: 256x256 / BK=64 / 8 waves (2Mx4N) / 8-phase schedule (T2+T3+T4+T5).
//
// LDS per buffer p (64 KiB @ p*65536): A[256][64]bf16 @0 (halves A0 rows0-127
// @0, A1 @16384), B @32768 (B0 @32768, B1 @49152). Row=128B=8x16B slots,
// physical slot = logical ^ (row&7), applied on BOTH pre-swizzled global src
// and ds_read addr (rule #21).
//
// Iteration u computes tiles 2u (buf0, phases 1-4) and 2u+1 (buf1, phases 5-8).
// Each phase: {4 a ds_reads [+8 b reads in ph1/5] | stage 1 half-tile} ->
// barrier -> lgkmcnt(0)+sched_barrier -> setprio(1) 16 MFMA setprio(0) -> barrier.
// Stage schedule (slot provably free at issue; all waves past the freeing
// barrier): ph1:(2u+1).A0  ph2:(2u+1).A1  ph3:(2u+2).B0  ph4:(2u+2).B1
//           ph5:(2u+2).A0  ph6:(2u+2).A1  ph7:(2u+3).B0  ph8:(2u+3).B1
// vmcnt(4) at ph4/ph8 only (2 newest half-tiles may stay in flight).
// ---------------------------------------------------------------------------
__global__ __launch_bounds__(512, 2) void gemm8p(const unsigned short* __restrict__ Ab,
                                                 const unsigned short* __restrict__ Bt,
                                                 float* __restrict__ C) {
    __shared__ __align__(16) char smem[2 * 65536];

    const int tid  = threadIdx.x;
    const int wave = tid >> 6;
    const int lane = tid & 63;

    // XCD-bijective swizzle (nwg = 512, % 8 == 0)
    const int nwg = gridDim.x;
    const int cpx = nwg >> 3;
    const int wg  = (blockIdx.x & 7) * cpx + (blockIdx.x >> 3);
    const int nbn = N_DIM / BN;                 // 16
    const int bm0 = (wg / nbn) * BM;
    const int bn0 = (wg % nbn) * BN;

    const int wr = wave >> 2;                   // 0..1 (M)
    const int wc = wave & 3;                    // 0..3 (N)

    // ---- staging (pre-swizzled global source) ----
    const int srow = tid >> 3;                          // 0..63 (row within 64-row chunk)
    const int lsw  = (lane & 7) ^ ((lane >> 3) & 7);    // logical slot this lane fetches
    const unsigned short* gA0 = Ab + (size_t)(bm0 + srow) * K_DIM + lsw * 8;
    const unsigned short* gB0 = Bt + (size_t)(bn0 + srow) * K_DIM + lsw * 8;

    // ---- ds_read addressing (swizzled; row&7 == lane&7 for all fragment rows) ----
    const int r16  = lane & 15;
    const int x7   = lane & 7;
    const int ksl0 = (((lane >> 4)    ) ^ x7) * 16;     // kk=0 slot
    const int ksl1 = (((lane >> 4) | 4) ^ x7) * 16;     // kk=1 slot
    const int aRow = (wr * 128 + r16) * 128;            // byte offset, A region
    const int bRow = (wc * 64  + r16) * 128 + 32768;    // byte offset, B region

    f32x4  acc[8][4] = {};
    bf16x8 b[4][2];

    // stage one 128x64 half-tile (2 x global_load_lds dwordx4 per thread)
#define STAGE_HALF(gbase, opoff, h, t, p) do {                                              \
    char* lds_ = smem + (p) * 65536 + (opoff) + (h) * 16384 + wave * 1024;                  \
    const unsigned short* g_ = (gbase) + (size_t)((h) * 128) * K_DIM + (t) * BK;            \
    __builtin_amdgcn_global_load_lds(                                                        \
        (const __attribute__((address_space(1))) unsigned int*)g_,                           \
        (__attribute__((address_space(3))) unsigned int*)lds_, 16, 0, 0);                    \
    __builtin_amdgcn_global_load_lds(                                                        \
        (const __attribute__((address_space(1))) unsigned int*)(g_ + (size_t)64 * K_DIM),    \
        (__attribute__((address_space(3))) unsigned int*)(lds_ + 8192), 16, 0, 0);           \
} while (0)

#define PHASE(P, Q, LOADB, STAGE_STMT, VM_STMT) do {                                        \
    const char* base_ = smem + (P) * 65536;                                                 \
    bf16x8 a_[2][2];                                                                        \
    if (LOADB) {                                                                            \
        _Pragma("unroll")                                                                   \
        for (int fn = 0; fn < 4; ++fn) {                                                    \
            b[fn][0] = *(const bf16x8*)(base_ + bRow + fn * 2048 + ksl0);                   \
            b[fn][1] = *(const bf16x8*)(base_ + bRow + fn * 2048 + ksl1);                   \
        }                                                                                   \
    }                                                                                       \
    a_[0][0] = *(const bf16x8*)(base_ + aRow + (Q) * 4096 + ksl0);                          \
    a_[0][1] = *(const bf16x8*)(base_ + aRow + (Q) * 4096 + ksl1);                          \
    a_[1][0] = *(const bf16x8*)(base_ + aRow + (Q) * 4096 + 2048 + ksl0);                   \
    a_[1][1] = *(const bf16x8*)(base_ + aRow + (Q) * 4096 + 2048 + ksl1);                   \
    STAGE_STMT;                                                                             \
    __builtin_amdgcn_s_barrier();                                                           \
    asm volatile("s_waitcnt lgkmcnt(0)" ::: "memory");                                      \
    __builtin_amdgcn_sched_barrier(0);                                                      \
    __builtin_amdgcn_s_setprio(1);                                                          \
    _Pragma("unroll")                                                                       \
    for (int fm = 0; fm < 2; ++fm)                                                          \
        _Pragma("unroll")                                                                   \
        for (int fn = 0; fn < 4; ++fn) {                                                    \
            acc[(Q)*2 + fm][fn] = __builtin_amdgcn_mfma_f32_16x16x32_bf16(                  \
                a_[fm][0], b[fn][0], acc[(Q)*2 + fm][fn], 0, 0, 0);                         \
            acc[(Q)*2 + fm][fn] = __builtin_amdgcn_mfma_f32_16x16x32_bf16(                  \
                a_[fm][1], b[fn][1], acc[(Q)*2 + fm][fn], 0, 0, 0);                         \
        }                                                                                   \
    __builtin_amdgcn_s_setprio(0);                                                          \
    VM_STMT;                                                                                \
    __builtin_amdgcn_s_barrier();                                                           \
} while (0)

    // ---- prologue: tile0 complete + tile1 B halves; allow t1.B in flight ----
    STAGE_HALF(gA0, 0,     0, 0, 0);
    STAGE_HALF(gA0, 0,     1, 0, 0);
    STAGE_HALF(gB0, 32768, 0, 0, 0);
    STAGE_HALF(gB0, 32768, 1, 0, 0);
    STAGE_HALF(gB0, 32768, 0, 1, 1);
    STAGE_HALF(gB0, 32768, 1, 1, 1);
    asm volatile("s_waitcnt vmcnt(4)" ::: "memory");
    __builtin_amdgcn_s_barrier();

    for (int u = 0; u < NITER; ++u) {
        const bool last = (u == NITER - 1);
        const int  t1 = 2 * u + 1, t2 = 2 * u + 2, t3 = 2 * u + 3;

        PHASE(0, 0, 1, { STAGE_HALF(gA0, 0, 0, t1, 1); }, {});
        PHASE(0, 1, 0, { STAGE_HALF(gA0, 0, 1, t1, 1); }, {});
        PHASE(0, 2, 0, { if (!last) STAGE_HALF(gB0, 32768, 0, t2, 0); }, {});
        PHASE(0, 3, 0, { if (!last) STAGE_HALF(gB0, 32768, 1, t2, 0); },
              { if (last) asm volatile("s_waitcnt vmcnt(0)" ::: "memory");
                else      asm volatile("s_waitcnt vmcnt(4)" ::: "memory"); });
        PHASE(1, 0, 1, { if (!last) STAGE_HALF(gA0, 0, 0, t2, 0); }, {});
        PHASE(1, 1, 0, { if (!last) STAGE_HALF(gA0, 0, 1, t2, 0); }, {});
        PHASE(1, 2, 0, { if (!last) STAGE_HALF(gB0, 32768, 0, t3, 1); }, {});
        PHASE(1, 3, 0, { if (!last) STAGE_HALF(gB0, 32768, 1, t3, 1); },
              { if (!last) asm volatile("s_waitcnt vmcnt(4)" ::: "memory"); });
    }
#undef PHASE
#undef STAGE_HALF

    // ---- epilogue: D col = lane&15, row = (lane>>4)*4 + r ----
    const int crow = (lane >> 4) * 4;
    const int ccol = lane & 15;
    float* Cb = C + (size_t)(bm0 + wr * 128 + crow) * N_DIM + (bn0 + wc * 64 + ccol);
#pragma unroll
    for (int fm = 0; fm < 8; ++fm)
#pragma unroll
        for (int fn = 0; fn < 4; ++fn)
#pragma unroll
            for (int r = 0; r < 4; ++r)
                Cb[(size_t)(fm * 16 + r) * N_DIM + fn * 16] = acc[fm][fn][r];
}

// ---------------------------------------------------------------------------
extern "C" void kernel_launch(void* const* d_in, const int* in_sizes, int n_in,
                              void* d_out, int out_size, void* d_ws, size_t ws_size,
                              hipStream_t stream) {
    const float* x = (const float*)d_in[0];   // (4,2048,2048) fp32
    const float* W = (const float*)d_in[1];   // (4096,2048) fp32
    float* out = (float*)d_out;               // (4,2048,4096) fp32

    unsigned short* xb = (unsigned short*)d_ws;                                      // 32 MB bf16 x
    unsigned short* wt = (unsigned short*)((char*)d_ws + (size_t)M_DIM * K_DIM * 2); // 16 MB WeffT

    build_weff<<<N_DIM, 256, 0, stream>>>(W, wt);
    cvt_x_kernel<<<(M_DIM * K_DIM) / 4 / 256, 256, 0, stream>>>(x, xb);

    dim3 grid((M_DIM / BM) * (N_DIM / BN));   // 512 blocks
    gemm8p<<<grid, 512, 0, stream>>>(xb, wt, out);
}